// Round 4
// baseline (1620.124 us; speedup 1.0000x reference)
//
#include <hip/hip_runtime.h>
#include <hip/hip_cooperative_groups.h>

typedef unsigned short u16;
using bf16x8 = __attribute__((ext_vector_type(8))) short;
using f32x4  = __attribute__((ext_vector_type(4))) float;

#define SQRT_HALF 0.70710678118f

__device__ __forceinline__ u16 f2bf(float f) {
    union { float f; unsigned int i; } x; x.f = f;
    unsigned int i = x.i;
    unsigned int r = (i + 0x7FFFu + ((i >> 16) & 1u)) >> 16;
    return (u16)r;
}
__device__ __forceinline__ float bf2f(u16 u) {
    union { unsigned int i; float f; } x; x.i = ((unsigned int)u) << 16; return x.f;
}
__device__ __forceinline__ float fastrcp(float x) {
    float r; asm("v_rcp_f32 %0, %1" : "=v"(r) : "v"(x)); return r;
}
__device__ __forceinline__ float sigm(float x) {
    return fastrcp(1.0f + __expf(-x));
}
__device__ __forceinline__ float tanh_f(float x) {
    float cx = fminf(fmaxf(x, -12.f), 12.f);
    float e = __expf(2.f * cx);
    return 1.0f - 2.0f * fastrcp(e + 1.0f);   // (e-1)/(e+1)
}

// async global->LDS, 16B per lane; LDS dest is wave-uniform base + lane*16.
__device__ __forceinline__ void gld16(const u16* g, u16* l) {
    __builtin_amdgcn_global_load_lds(
        (const __attribute__((address_space(1))) void*)g,
        (__attribute__((address_space(3))) void*)l,
        16, 0, 0);
}

// ---------------- shared GEMM tile (layers 1..9) ----------------
// A: [M,512] bf16 row-major. Wg: [3][256][512] bf16. Out: Y [M,256] bf16.
// Tile 128M x 64co x 3conv, BK=32. global_load_lds staging, linear LDS dest +
// inverse-swizzled global source, swizzled ds_read. Depth-2 pipeline with
// counted vmcnt(5), never drained mid-loop. Entry s_barrier protects LDS
// reuse across consecutive tiles in the persistent kernel.
__device__ __forceinline__ void gemm_tile(
        int tileIdx, int mtiles,
        const u16* __restrict__ A, const u16* __restrict__ Wg,
        const float* __restrict__ ca_in, const float* __restrict__ ca_g,
        const float* __restrict__ br, u16* __restrict__ Y,
        int M, int lg, int n_start,
        u16* A0, u16* A1, u16* B0, u16* B1) {
    asm volatile("s_barrier" ::: "memory");   // prev tile fully done with LDS

    int mtile, cotile;
    if ((mtiles & 7) == 0) {
        int g = tileIdx >> 5, r = tileIdx & 31;  // 32-tile group = 8 mtiles x 4 cotiles
        mtile  = g * 8 + (r & 7);
        cotile = r >> 3;
    } else {
        mtile = tileIdx >> 2; cotile = tileIdx & 3;
    }
    int m0  = mtile * 128;
    int co0 = cotile * 64;
    int tid = threadIdx.x;
    int lane = tid & 63, wave = tid >> 6;
    int wm = wave & 1, wc = wave >> 1;
    int q = lane >> 4, r16 = lane & 15;

    const u16* agp[2]; unsigned aoff[2];
    #pragma unroll
    for (int i = 0; i < 2; ++i) {
        int c = i * 256 + tid;
        int row = c >> 2, s = c & 3;
        int m = m0 + row;
        int msafe = m < M ? m : (M - 1);
        agp[i] = A + (size_t)msafe * 512 + (s ^ ((row >> 1) & 3)) * 8;
        aoff[i] = (unsigned)c * 8;
    }
    const u16* bgp[3]; unsigned boff[3];
    #pragma unroll
    for (int i = 0; i < 3; ++i) {
        int c = i * 256 + tid;
        int row = c >> 2, s = c & 3;
        int conv = row >> 6, col = row & 63;
        bgp[i] = Wg + ((size_t)conv * 256 + co0 + col) * 512 + (s ^ ((row >> 1) & 3)) * 8;
        boff[i] = (unsigned)c * 8;
    }

    f32x4 acc[3][4][2] = {};

    auto doIssue = [&](int ktn, u16* Al, u16* Bl) {
        #pragma unroll
        for (int i = 0; i < 2; ++i) gld16(agp[i] + ktn * 32, &Al[aoff[i]]);
        #pragma unroll
        for (int i = 0; i < 3; ++i) gld16(bgp[i] + ktn * 32, &Bl[boff[i]]);
    };
    auto doComp = [&](const u16* Al, const u16* Bl) {
        bf16x8 af[4], bfr[3][2];
        #pragma unroll
        for (int ms = 0; ms < 4; ++ms) {
            int row = wm * 64 + ms * 16 + r16;
            af[ms] = *(const bf16x8*)(&Al[row * 32 + ((q ^ ((row >> 1) & 3)) * 8)]);
        }
        #pragma unroll
        for (int cv = 0; cv < 3; ++cv)
            #pragma unroll
            for (int cs = 0; cs < 2; ++cs) {
                int row = cv * 64 + wc * 32 + cs * 16 + r16;
                bfr[cv][cs] = *(const bf16x8*)(&Bl[row * 32 + ((q ^ ((row >> 1) & 3)) * 8)]);
            }
        __builtin_amdgcn_s_setprio(1);
        #pragma unroll
        for (int cv = 0; cv < 3; ++cv)
            #pragma unroll
            for (int ms = 0; ms < 4; ++ms)
                #pragma unroll
                for (int cs = 0; cs < 2; ++cs)
                    acc[cv][ms][cs] = __builtin_amdgcn_mfma_f32_16x16x32_bf16(
                        af[ms], bfr[cv][cs], acc[cv][ms][cs], 0, 0, 0);
        __builtin_amdgcn_s_setprio(0);
    };

    doIssue(0, A0, B0);
    doIssue(1, A1, B1);
    asm volatile("s_waitcnt vmcnt(5)\n\ts_barrier" ::: "memory");

    #pragma unroll
    for (int kt2 = 0; kt2 < 7; ++kt2) {
        doComp(A0, B0);
        asm volatile("s_waitcnt lgkmcnt(0)\n\ts_barrier" ::: "memory");
        doIssue(2 * kt2 + 2, A0, B0);
        asm volatile("s_waitcnt vmcnt(5)\n\ts_barrier" ::: "memory");
        doComp(A1, B1);
        asm volatile("s_waitcnt lgkmcnt(0)\n\ts_barrier" ::: "memory");
        doIssue(2 * kt2 + 3, A1, B1);
        asm volatile("s_waitcnt vmcnt(5)\n\ts_barrier" ::: "memory");
    }
    doComp(A0, B0);
    asm volatile("s_waitcnt lgkmcnt(0)\n\ts_barrier" ::: "memory");
    asm volatile("s_waitcnt vmcnt(0)\n\ts_barrier" ::: "memory");
    doComp(A1, B1);

    #pragma unroll
    for (int ms = 0; ms < 4; ++ms) {
        #pragma unroll
        for (int reg = 0; reg < 4; ++reg) {
            int m = m0 + wm * 64 + ms * 16 + q * 4 + reg;
            if (m >= M) continue;
            int n = n_start + (m >> lg);
            #pragma unroll
            for (int cs = 0; cs < 2; ++cs) {
                int co = co0 + wc * 32 + cs * 16 + r16;
                float vin = acc[0][ms][cs][reg] + ca_in[n * 256 + co];
                float vg  = acc[1][ms][cs][reg] + ca_g [n * 256 + co];
                float vr  = acc[2][ms][cs][reg] + br[co];
                float o = (tanh_f(vin) * sigm(vg) + vr) * SQRT_HALF;
                Y[(size_t)m * 256 + co] = f2bf(o);
            }
        }
    }
}

// ---------------- fallback-path kernels (R3, known good) ----------------
__global__ void cond_kernel(const float* __restrict__ mgc, const float* __restrict__ cond_w,
                            const float* __restrict__ cond_b, float* __restrict__ cond2) {
    int j = blockIdx.x * 256 + threadIdx.x;
    if (j >= 24000) return;
    int f = j / 12000, jj = j % 12000;
    float s = cond_b[jj];
    const float* wrow = cond_w + (size_t)jj * 60;
    const float* mrow = mgc + f * 60;
    for (int c = 0; c < 60; ++c) s += mrow[c] * wrow[c];
    float v = tanh_f(s);
    int n = f * 200 + jj / 60, cc = jj % 60;
    cond2[n * 60 + cc] = v;
}

__global__ void condadd_kernel(const float* __restrict__ cond2,
                               const float* __restrict__ cw_in, const float* __restrict__ cb_in,
                               const float* __restrict__ cw_g,  const float* __restrict__ cb_g,
                               const float* __restrict__ l0_bin, const float* __restrict__ lb_in,
                               const float* __restrict__ l0_bg,  const float* __restrict__ lb_g,
                               float* __restrict__ ca_in, float* __restrict__ ca_g) {
    int idx = blockIdx.x * 256 + threadIdx.x;
    if (idx >= 10 * 400 * 256) return;
    int co = idx & 255;
    int n  = (idx >> 8) % 400;
    int l  = idx / (400 * 256);
    float si = cb_in[l * 256 + co] + (l == 0 ? l0_bin[co] : lb_in[(l - 1) * 256 + co]);
    float sg = cb_g [l * 256 + co] + (l == 0 ? l0_bg [co] : lb_g [(l - 1) * 256 + co]);
    const float* cn = cond2 + n * 60;
    const float* wi = cw_in + (size_t)(l * 256 + co) * 60;
    const float* wg = cw_g  + (size_t)(l * 256 + co) * 60;
    for (int c = 0; c < 60; ++c) {
        float cv = cn[c];
        si += cv * wi[c];
        sg += cv * wg[c];
    }
    ca_in[idx] = si;
    ca_g[idx]  = sg;
}

__global__ void wreorder_kernel(const float* __restrict__ lw_in, const float* __restrict__ lw_g,
                                const float* __restrict__ lw_r, u16* __restrict__ Wg) {
    int idx = blockIdx.x * 256 + threadIdx.x;
    if (idx >= 9 * 256 * 512) return;
    int kk = idx & 511;
    int co = (idx >> 9) & 255;
    int l  = idx >> 17;
    int k = kk >> 8, ci = kk & 255;
    size_t src = ((size_t)(l * 256 + co) * 256 + ci) * 2 + k;
    size_t dst = (size_t)l * 3 * 131072 + (size_t)co * 512 + kk;
    Wg[dst]              = f2bf(lw_in[src]);
    Wg[dst + 131072]     = f2bf(lw_g[src]);
    Wg[dst + 2 * 131072] = f2bf(lw_r[src]);
}

__global__ void l0_kernel(const float* __restrict__ signal,
                          const float* __restrict__ l0_win, const float* __restrict__ l0_wg,
                          const float* __restrict__ l0_wr,  const float* __restrict__ l0_br,
                          const float* __restrict__ ca_in0, const float* __restrict__ ca_g0,
                          u16* __restrict__ Y0, int n_start) {
    int b = blockIdx.x;
    int tg = b & 127, n_local = b >> 7;
    int n = n_start + n_local;
    int ci = threadIdx.x;
    float wi0 = l0_win[ci * 2], wi1 = l0_win[ci * 2 + 1];
    float wg0 = l0_wg [ci * 2], wg1 = l0_wg [ci * 2 + 1];
    float wr0 = l0_wr [ci * 2], wr1 = l0_wr [ci * 2 + 1];
    float cain = ca_in0[n * 256 + ci], cag = ca_g0[n * 256 + ci], br = l0_br[ci];
    for (int i = 0; i < 4; ++i) {
        int t = tg * 4 + i;
        float s0 = signal[n + 2 * t];
        float s1 = signal[n + 2 * t + 1];
        float vin = wi0 * s0 + wi1 * s1 + cain;
        float vg  = wg0 * s0 + wg1 * s1 + cag;
        float vr  = wr0 * s0 + wr1 * s1 + br;
        float o = (tanh_f(vin) * sigm(vg) + vr) * SQRT_HALF;
        Y0[((size_t)n_local * 512 + t) * 256 + ci] = f2bf(o);
    }
}

__global__ __launch_bounds__(256, 3) void gemm_layer_kernel(
        const u16* __restrict__ A, const u16* __restrict__ Wg,
        const float* __restrict__ ca_in, const float* __restrict__ ca_g,
        const float* __restrict__ br, u16* __restrict__ Y,
        int M, int lg, int n_start) {
    __shared__ __attribute__((aligned(16))) u16 A0[128 * 32];
    __shared__ __attribute__((aligned(16))) u16 A1[128 * 32];
    __shared__ __attribute__((aligned(16))) u16 B0[192 * 32];
    __shared__ __attribute__((aligned(16))) u16 B1[192 * 32];
    int mtiles = (M + 127) >> 7;
    gemm_tile(blockIdx.x, mtiles, A, Wg, ca_in, ca_g, br, Y, M, lg, n_start,
              A0, A1, B0, B1);
}

__global__ __launch_bounds__(256) void head_kernel(
        const u16* __restrict__ Y9, const float* __restrict__ pre_w, const float* __restrict__ pre_b,
        const float* __restrict__ mean_w, const float* __restrict__ mean_b,
        const float* __restrict__ std_w,  const float* __restrict__ std_b,
        const float* __restrict__ logit_w, const float* __restrict__ logit_b,
        float* __restrict__ out, int n_start) {
    __shared__ float xin[256];
    __shared__ float pre[256];
    int n_local = blockIdx.x;
    int n = n_start + n_local;
    int t = threadIdx.x;
    xin[t] = bf2f(Y9[(size_t)n_local * 256 + t]);
    __syncthreads();
    float s = pre_b[t];
    const float* wrow = pre_w + (size_t)t * 256;
    for (int c = 0; c < 256; ++c) s += xin[c] * wrow[c];
    pre[t] = fmaxf(s, 0.f);
    __syncthreads();
    if (t < 30) {
        int head = t / 10, mix = t % 10;
        const float* w  = head == 0 ? mean_w : (head == 1 ? std_w : logit_w);
        const float* bb = head == 0 ? mean_b : (head == 1 ? std_b : logit_b);
        float s2 = bb[mix];
        const float* wr = w + mix * 256;
        for (int c = 0; c < 256; ++c) s2 += pre[c] * wr[c];
        out[head * 4000 + n * 10 + mix] = s2;
    }
}

// ---------------- persistent cooperative mega-kernel ----------------
struct MegaParams {
    const float *signal, *mgc, *cond_w, *cond_b;
    const float *l0_win, *l0_bin, *l0_wg, *l0_bg, *l0_wr, *l0_br;
    const float *lw_in, *lb_in, *lw_g, *lb_g, *lw_r, *lb_r;
    const float *cw_in, *cb_in, *cw_g, *cb_g;
    const float *pre_w, *pre_b, *mean_w, *mean_b, *std_w, *std_b, *logit_w, *logit_b;
    u16* Wg; float* ca_in; float* ca_g;
    u16* bufA; u16* bufB;
    float* out;
};

__global__ __launch_bounds__(256, 3) void mega_kernel(MegaParams P) {
    cooperative_groups::grid_group grid = cooperative_groups::this_grid();
    __shared__ __attribute__((aligned(16))) u16 A0[128 * 32];
    __shared__ __attribute__((aligned(16))) u16 A1[128 * 32];
    __shared__ __attribute__((aligned(16))) u16 B0[192 * 32];
    __shared__ __attribute__((aligned(16))) u16 B1[192 * 32];
    __shared__ float c2[60];
    __shared__ float xin[256];
    __shared__ float pre[256];

    int b = blockIdx.x, t = threadIdx.x, nb = gridDim.x;

    // ---- P0: per-n fused cond+condadd (cond2 row stays in LDS), plus wreorder ----
    for (int n = b; n < 400; n += nb) {
        __syncthreads();                     // protect c2 from previous iteration
        if (t < 60) {
            int f = n / 200;
            int jj = (n % 200) * 60 + t;
            float s = P.cond_b[jj];
            const float* wrow = P.cond_w + (size_t)jj * 60;
            const float* mrow = P.mgc + f * 60;
            for (int cc = 0; cc < 60; ++cc) s += mrow[cc] * wrow[cc];
            c2[t] = tanh_f(s);
        }
        __syncthreads();
        int co = t;
        for (int l = 0; l < 10; ++l) {
            float si = P.cb_in[l * 256 + co] + (l == 0 ? P.l0_bin[co] : P.lb_in[(l - 1) * 256 + co]);
            float sg = P.cb_g [l * 256 + co] + (l == 0 ? P.l0_bg [co] : P.lb_g [(l - 1) * 256 + co]);
            const float* wi = P.cw_in + (size_t)(l * 256 + co) * 60;
            const float* wg = P.cw_g  + (size_t)(l * 256 + co) * 60;
            for (int cc = 0; cc < 60; ++cc) {
                float cv = c2[cc];
                si += cv * wi[cc];
                sg += cv * wg[cc];
            }
            P.ca_in[l * 102400 + n * 256 + co] = si;
            P.ca_g [l * 102400 + n * 256 + co] = sg;
        }
    }
    for (int idx = b * 256 + t; idx < 9 * 256 * 512; idx += nb * 256) {
        int kk = idx & 511;
        int co = (idx >> 9) & 255;
        int l  = idx >> 17;
        int k = kk >> 8, ci = kk & 255;
        size_t src = ((size_t)(l * 256 + co) * 256 + ci) * 2 + k;
        size_t dst = (size_t)l * 3 * 131072 + (size_t)co * 512 + kk;
        P.Wg[dst]              = f2bf(P.lw_in[src]);
        P.Wg[dst + 131072]     = f2bf(P.lw_g[src]);
        P.Wg[dst + 2 * 131072] = f2bf(P.lw_r[src]);
    }
    __threadfence(); grid.sync(); __threadfence();

    // ---- P1: layer 0, distributed over all blocks (row m = n*512 + t) ----
    {
        int ci = t;
        float wi0 = P.l0_win[ci * 2], wi1 = P.l0_win[ci * 2 + 1];
        float wg0 = P.l0_wg [ci * 2], wg1 = P.l0_wg [ci * 2 + 1];
        float wr0 = P.l0_wr [ci * 2], wr1 = P.l0_wr [ci * 2 + 1];
        float brv = P.l0_br[ci];
        for (int m = b; m < 400 * 512; m += nb) {
            int n = m >> 9, tt = m & 511;
            float s0 = P.signal[n + 2 * tt];
            float s1 = P.signal[n + 2 * tt + 1];
            float cain = P.ca_in[n * 256 + ci];
            float cag  = P.ca_g [n * 256 + ci];
            float vin = wi0 * s0 + wi1 * s1 + cain;
            float vg  = wg0 * s0 + wg1 * s1 + cag;
            float vr  = wr0 * s0 + wr1 * s1 + brv;
            P.bufA[(size_t)m * 256 + ci] = f2bf((tanh_f(vin) * sigm(vg) + vr) * SQRT_HALF);
        }
    }
    __threadfence(); grid.sync(); __threadfence();

    // ---- layers 1..9: grid-stride over tiles, grid.sync between layers ----
    const u16* src = P.bufA;
    u16* dst = P.bufB;
    for (int layer = 1; layer <= 9; ++layer) {
        int lg = 9 - layer;
        int M = 400 << lg;
        int mtiles = (M + 127) >> 7;
        int ntiles = mtiles * 4;
        const u16* Wgl = P.Wg + (size_t)(layer - 1) * 3 * 131072;
        const float* cai = P.ca_in + (size_t)layer * 102400;
        const float* cag = P.ca_g  + (size_t)layer * 102400;
        const float* brl = P.lb_r + (layer - 1) * 256;
        for (int tile = b; tile < ntiles; tile += nb)
            gemm_tile(tile, mtiles, src, Wgl, cai, cag, brl, dst, M, lg, 0,
                      A0, A1, B0, B1);
        __threadfence(); grid.sync(); __threadfence();
        const u16* tsw = src; src = dst; dst = (u16*)tsw;
    }

    // ---- head: per-n over blocks ----
    for (int n = b; n < 400; n += nb) {
        __syncthreads();
        xin[t] = bf2f(src[(size_t)n * 256 + t]);
        __syncthreads();
        float s = P.pre_b[t];
        const float* wrow = P.pre_w + (size_t)t * 256;
        for (int c = 0; c < 256; ++c) s += xin[c] * wrow[c];
        pre[t] = fmaxf(s, 0.f);
        __syncthreads();
        if (t < 30) {
            int head = t / 10, mix = t % 10;
            const float* w  = head == 0 ? P.mean_w : (head == 1 ? P.std_w : P.logit_w);
            const float* bb = head == 0 ? P.mean_b : (head == 1 ? P.std_b : P.logit_b);
            float s2 = bb[mix];
            const float* wr = w + mix * 256;
            for (int c = 0; c < 256; ++c) s2 += pre[c] * wr[c];
            P.out[head * 4000 + n * 10 + mix] = s2;
        }
    }
}

extern "C" void kernel_launch(void* const* d_in, const int* in_sizes, int n_in,
                              void* d_out, int out_size, void* d_ws, size_t ws_size,
                              hipStream_t stream) {
    const float* signal  = (const float*)d_in[0];
    const float* mgc     = (const float*)d_in[1];
    const float* cond_w  = (const float*)d_in[2];
    const float* cond_b  = (const float*)d_in[3];
    const float* l0_win  = (const float*)d_in[4];
    const float* l0_bin  = (const float*)d_in[5];
    const float* l0_wg   = (const float*)d_in[6];
    const float* l0_bg   = (const float*)d_in[7];
    const float* l0_wr   = (const float*)d_in[8];
    const float* l0_br   = (const float*)d_in[9];
    const float* lw_in   = (const float*)d_in[10];
    const float* lb_in   = (const float*)d_in[11];
    const float* lw_g    = (const float*)d_in[12];
    const float* lb_g    = (const float*)d_in[13];
    const float* lw_r    = (const float*)d_in[14];
    const float* lb_r    = (const float*)d_in[15];
    const float* cw_in   = (const float*)d_in[16];
    const float* cb_in   = (const float*)d_in[17];
    const float* cw_g    = (const float*)d_in[18];
    const float* cb_g    = (const float*)d_in[19];
    const float* pre_w   = (const float*)d_in[20];
    const float* pre_b   = (const float*)d_in[21];
    const float* mean_w  = (const float*)d_in[22];
    const float* mean_b  = (const float*)d_in[23];
    const float* std_w   = (const float*)d_in[24];
    const float* std_b   = (const float*)d_in[25];
    const float* logit_w = (const float*)d_in[26];
    const float* logit_b = (const float*)d_in[27];
    float* out = (float*)d_out;

    char* p = (char*)d_ws;
    auto alloc = [&](size_t bytes) -> char* {
        char* r = p; p += (bytes + 255) & ~(size_t)255; return r;
    };
    u16*   Wg    = (u16*)alloc(7077888);        // 9*3*256*512 bf16
    float* ca_in = (float*)alloc(4096000);      // 10*400*256 f32
    float* ca_g  = (float*)alloc(4096000);
    float* cond2 = (float*)alloc(96000);        // 400*60 f32 (fallback path only)
    size_t fixedBytes = (size_t)(p - (char*)d_ws);

    int c = 1;
    while (c < 16 && fixedBytes + (104857600ull + 52428800ull) / c + 4096 > ws_size) c <<= 1;
    u16* bufA = (u16*)alloc(104857600ull / c);
    u16* bufB = (u16*)alloc(52428800ull / c);
    int n_count = 400 / c;

    bool megaOk = false;
    if (c == 1) {
        static int s_grid = 0;
        if (s_grid == 0) {
            int occ = 0;
            if (hipOccupancyMaxActiveBlocksPerMultiprocessor(&occ, mega_kernel, 256, 0)
                    != hipSuccess || occ < 1) occ = 2;
            if (occ > 3) occ = 3;
            int ncu = 256;
            hipDeviceProp_t props;
            int dev = 0;
            if (hipGetDevice(&dev) == hipSuccess &&
                hipGetDeviceProperties(&props, dev) == hipSuccess &&
                props.multiProcessorCount > 0) ncu = props.multiProcessorCount;
            s_grid = occ * ncu;
        }
        MegaParams prm{ signal, mgc, cond_w, cond_b,
                        l0_win, l0_bin, l0_wg, l0_bg, l0_wr, l0_br,
                        lw_in, lb_in, lw_g, lb_g, lw_r, lb_r,
                        cw_in, cb_in, cw_g, cb_g,
                        pre_w, pre_b, mean_w, mean_b, std_w, std_b, logit_w, logit_b,
                        Wg, ca_in, ca_g, bufA, bufB, out };
        void* kp[] = { (void*)&prm };
        hipError_t e = hipLaunchCooperativeKernel((const void*)mega_kernel,
                                                  dim3(s_grid), dim3(256), kp, 0, stream);
        if (e == hipSuccess) megaOk = true;
        else (void)hipGetLastError();   // clear, fall back
    }

    if (!megaOk) {
        cond_kernel<<<94, 256, 0, stream>>>(mgc, cond_w, cond_b, cond2);
        condadd_kernel<<<4000, 256, 0, stream>>>(cond2, cw_in, cb_in, cw_g, cb_g,
                                                 l0_bin, lb_in, l0_bg, lb_g, ca_in, ca_g);
        wreorder_kernel<<<4608, 256, 0, stream>>>(lw_in, lw_g, lw_r, Wg);
        for (int ch = 0; ch < c; ++ch) {
            int n_start = ch * n_count;
            l0_kernel<<<n_count * 128, 256, 0, stream>>>(signal, l0_win, l0_wg, l0_wr, l0_br,
                                                         ca_in, ca_g, bufA, n_start);
            u16* src = bufA;
            u16* dst = bufB;
            for (int layer = 1; layer <= 9; ++layer) {
                int lg = 9 - layer;
                int M = n_count << lg;
                int mtiles = (M + 127) / 128;
                gemm_layer_kernel<<<mtiles * 4, 256, 0, stream>>>(
                    src, Wg + (size_t)(layer - 1) * 3 * 131072,
                    ca_in + (size_t)layer * 102400, ca_g + (size_t)layer * 102400,
                    lb_r + (layer - 1) * 256, dst, M, lg, n_start);
                u16* tswap = src; src = dst; dst = tswap;
            }
            head_kernel<<<n_count, 256, 0, stream>>>(src, pre_w, pre_b, mean_w, mean_b,
                                                     std_w, std_b, logit_w, logit_b, out, n_start);
        }
    }
}

// Round 5
// 567.355 us; speedup vs baseline: 2.8556x; 2.8556x over previous
//
#include <hip/hip_runtime.h>

typedef unsigned short u16;
using bf16x8 = __attribute__((ext_vector_type(8))) short;
using f32x4  = __attribute__((ext_vector_type(4))) float;

#define SQRT_HALF 0.70710678118f

__device__ __forceinline__ u16 f2bf(float f) {
    union { float f; unsigned int i; } x; x.f = f;
    unsigned int i = x.i;
    unsigned int r = (i + 0x7FFFu + ((i >> 16) & 1u)) >> 16;
    return (u16)r;
}
__device__ __forceinline__ float bf2f(u16 u) {
    union { unsigned int i; float f; } x; x.i = ((unsigned int)u) << 16; return x.f;
}
__device__ __forceinline__ float fastrcp(float x) {
    float r; asm("v_rcp_f32 %0, %1" : "=v"(r) : "v"(x)); return r;
}
__device__ __forceinline__ float sigm(float x) {
    return fastrcp(1.0f + __expf(-x));
}
__device__ __forceinline__ float tanh_f(float x) {
    float cx = fminf(fmaxf(x, -12.f), 12.f);
    float e = __expf(2.f * cx);
    return 1.0f - 2.0f * fastrcp(e + 1.0f);   // (e-1)/(e+1)
}

// async global->LDS, 16B per lane; LDS dest is wave-uniform base + lane*16.
__device__ __forceinline__ void gld16(const u16* g, u16* l) {
    __builtin_amdgcn_global_load_lds(
        (const __attribute__((address_space(1))) void*)g,
        (__attribute__((address_space(3))) void*)l,
        16, 0, 0);
}

// ---------- fused prep: cond+condadd (blocks<400, per-n) + wreorder ----------
__global__ __launch_bounds__(256) void prep_kernel(
        const float* __restrict__ mgc, const float* __restrict__ cond_w,
        const float* __restrict__ cond_b,
        const float* __restrict__ cw_in, const float* __restrict__ cb_in,
        const float* __restrict__ cw_g,  const float* __restrict__ cb_g,
        const float* __restrict__ l0_bin, const float* __restrict__ lb_in,
        const float* __restrict__ l0_bg,  const float* __restrict__ lb_g,
        const float* __restrict__ lw_in, const float* __restrict__ lw_g,
        const float* __restrict__ lw_r,
        float* __restrict__ ca_in, float* __restrict__ ca_g, u16* __restrict__ Wg) {
    int b = blockIdx.x, t = threadIdx.x;
    if (b < 400) {
        __shared__ float c2[60];
        int n = b;
        if (t < 60) {
            int f = n / 200;
            int jj = (n % 200) * 60 + t;
            float s = cond_b[jj];
            const float* wrow = cond_w + (size_t)jj * 60;
            const float* mrow = mgc + f * 60;
            for (int cc = 0; cc < 60; ++cc) s += mrow[cc] * wrow[cc];
            c2[t] = tanh_f(s);
        }
        __syncthreads();
        int co = t;
        for (int l = 0; l < 10; ++l) {
            float si = cb_in[l * 256 + co] + (l == 0 ? l0_bin[co] : lb_in[(l - 1) * 256 + co]);
            float sg = cb_g [l * 256 + co] + (l == 0 ? l0_bg [co] : lb_g [(l - 1) * 256 + co]);
            const float* wi = cw_in + (size_t)(l * 256 + co) * 60;
            const float* wg = cw_g  + (size_t)(l * 256 + co) * 60;
            for (int cc = 0; cc < 60; ++cc) {
                float cv = c2[cc];
                si += cv * wi[cc];
                sg += cv * wg[cc];
            }
            ca_in[l * 102400 + n * 256 + co] = si;
            ca_g [l * 102400 + n * 256 + co] = sg;
        }
    } else {
        int idx = (b - 400) * 256 + t;
        if (idx < 9 * 256 * 512) {
            int kk = idx & 511;
            int co = (idx >> 9) & 255;
            int l  = idx >> 17;
            int k = kk >> 8, ci = kk & 255;
            size_t src = ((size_t)(l * 256 + co) * 256 + ci) * 2 + k;
            size_t dst = (size_t)l * 3 * 131072 + (size_t)co * 512 + kk;
            Wg[dst]              = f2bf(lw_in[src]);
            Wg[dst + 131072]     = f2bf(lw_g[src]);
            Wg[dst + 2 * 131072] = f2bf(lw_r[src]);
        }
    }
}

// ---------- layer 0 (unchanged, R3-verified) ----------
__global__ void l0_kernel(const float* __restrict__ signal,
                          const float* __restrict__ l0_win, const float* __restrict__ l0_wg,
                          const float* __restrict__ l0_wr,  const float* __restrict__ l0_br,
                          const float* __restrict__ ca_in0, const float* __restrict__ ca_g0,
                          u16* __restrict__ Y0, int n_start) {
    int b = blockIdx.x;
    int tg = b & 127, n_local = b >> 7;
    int n = n_start + n_local;
    int ci = threadIdx.x;
    float wi0 = l0_win[ci * 2], wi1 = l0_win[ci * 2 + 1];
    float wg0 = l0_wg [ci * 2], wg1 = l0_wg [ci * 2 + 1];
    float wr0 = l0_wr [ci * 2], wr1 = l0_wr [ci * 2 + 1];
    float cain = ca_in0[n * 256 + ci], cag = ca_g0[n * 256 + ci], br = l0_br[ci];
    for (int i = 0; i < 4; ++i) {
        int t = tg * 4 + i;
        float s0 = signal[n + 2 * t];
        float s1 = signal[n + 2 * t + 1];
        float vin = wi0 * s0 + wi1 * s1 + cain;
        float vg  = wg0 * s0 + wg1 * s1 + cag;
        float vr  = wr0 * s0 + wr1 * s1 + br;
        float o = (tanh_f(vin) * sigm(vg) + vr) * SQRT_HALF;
        Y0[((size_t)n_local * 512 + t) * 256 + ci] = f2bf(o);
    }
}

// ---------- templated fused 3-conv GEMM + gating (layers 1..9) ----------
// BK=32: R3-verified exact geometry (LDS 40KB, 3 blk/CU, 16 K-steps, vmcnt(5)).
// BK=64: R0-verified swizzle geometry + gld16 pipeline (LDS 80KB, 2 blk/CU,
//        8 K-steps, vmcnt(10)) — halves barrier pairs for latency-floor layers.
template<int BK>
__global__ __launch_bounds__(256, BK == 32 ? 3 : 2) void gemm_layer_kernel(
        const u16* __restrict__ A, const u16* __restrict__ Wg,
        const float* __restrict__ ca_in, const float* __restrict__ ca_g,
        const float* __restrict__ br, u16* __restrict__ Y,
        int M, int lg, int n_start) {
    constexpr int AC  = BK / 16;        // A chunks per thread per batch
    constexpr int BC  = (3 * BK) / 32;  // B chunks per thread per batch
    constexpr int SL  = BK / 8;         // 16B slots per row
    constexpr int RSH = (BK == 32) ? 2 : 3;  // log2(slots per row)
    constexpr int NS  = 512 / BK;       // K-steps

    __shared__ __attribute__((aligned(16))) u16 A0[128 * BK];
    __shared__ __attribute__((aligned(16))) u16 A1[128 * BK];
    __shared__ __attribute__((aligned(16))) u16 B0[192 * BK];
    __shared__ __attribute__((aligned(16))) u16 B1[192 * BK];

    int mtiles = (M + 127) >> 7;
    int b = blockIdx.x;
    int mtile, cotile;
    if ((mtiles & 7) == 0) {
        int g = b >> 5, r = b & 31;         // 32-block group = 8 mtiles x 4 cotiles
        mtile  = g * 8 + (r & 7);           // r&7 == b%8 == XCD id
        cotile = r >> 3;
    } else {
        mtile = b >> 2; cotile = b & 3;
    }
    int m0  = mtile * 128;
    int co0 = cotile * 64;
    int tid = threadIdx.x;
    int lane = tid & 63, wave = tid >> 6;
    int wm = wave & 1, wc = wave >> 1;
    int q = lane >> 4, r16 = lane & 15;

    auto swz = [](int row) { return (BK == 32) ? ((row >> 1) & 3) : (row & 7); };

    const u16* agp[AC]; unsigned aoff[AC];
    #pragma unroll
    for (int i = 0; i < AC; ++i) {
        int c = i * 256 + tid;
        int row = c >> RSH, s = c & (SL - 1);
        int m = m0 + row;
        int msafe = m < M ? m : (M - 1);
        agp[i] = A + (size_t)msafe * 512 + (s ^ swz(row)) * 8;
        aoff[i] = (unsigned)c * 8;
    }
    const u16* bgp[BC]; unsigned boff[BC];
    #pragma unroll
    for (int i = 0; i < BC; ++i) {
        int c = i * 256 + tid;
        int row = c >> RSH, s = c & (SL - 1);
        int conv = row >> 6, col = row & 63;
        bgp[i] = Wg + ((size_t)conv * 256 + co0 + col) * 512 + (s ^ swz(row)) * 8;
        boff[i] = (unsigned)c * 8;
    }

    f32x4 acc[3][4][2] = {};

    auto doIssue = [&](int ktn, u16* Al, u16* Bl) {
        #pragma unroll
        for (int i = 0; i < AC; ++i) gld16(agp[i] + ktn * BK, &Al[aoff[i]]);
        #pragma unroll
        for (int i = 0; i < BC; ++i) gld16(bgp[i] + ktn * BK, &Bl[boff[i]]);
    };
    auto doComp = [&](const u16* Al, const u16* Bl) {
        #pragma unroll
        for (int ks = 0; ks < BK / 32; ++ks) {
            bf16x8 af[4], bfr[3][2];
            #pragma unroll
            for (int ms = 0; ms < 4; ++ms) {
                int row = wm * 64 + ms * 16 + r16;
                af[ms] = *(const bf16x8*)(&Al[row * BK + (((ks * 4 + q) ^ swz(row)) * 8)]);
            }
            #pragma unroll
            for (int cv = 0; cv < 3; ++cv)
                #pragma unroll
                for (int cs = 0; cs < 2; ++cs) {
                    int row = cv * 64 + wc * 32 + cs * 16 + r16;
                    bfr[cv][cs] = *(const bf16x8*)(&Bl[row * BK + (((ks * 4 + q) ^ swz(row)) * 8)]);
                }
            __builtin_amdgcn_s_setprio(1);
            #pragma unroll
            for (int cv = 0; cv < 3; ++cv)
                #pragma unroll
                for (int ms = 0; ms < 4; ++ms)
                    #pragma unroll
                    for (int cs = 0; cs < 2; ++cs)
                        acc[cv][ms][cs] = __builtin_amdgcn_mfma_f32_16x16x32_bf16(
                            af[ms], bfr[cv][cs], acc[cv][ms][cs], 0, 0, 0);
            __builtin_amdgcn_s_setprio(0);
        }
    };
    auto waitv = []() {
        if constexpr (BK == 32)
            asm volatile("s_waitcnt vmcnt(5)\n\ts_barrier" ::: "memory");
        else
            asm volatile("s_waitcnt vmcnt(10)\n\ts_barrier" ::: "memory");
    };

    // prologue: batches 0 and 1 in flight; wait only batch 0.
    doIssue(0, A0, B0);
    doIssue(1, A1, B1);
    waitv();

    #pragma unroll
    for (int kt2 = 0; kt2 < NS / 2 - 1; ++kt2) {
        doComp(A0, B0);                                                 // batch 2*kt2
        asm volatile("s_waitcnt lgkmcnt(0)\n\ts_barrier" ::: "memory"); // waves done reading A0/B0
        doIssue(2 * kt2 + 2, A0, B0);
        waitv();                                                        // batch 2*kt2+1 landed
        doComp(A1, B1);                                                 // batch 2*kt2+1
        asm volatile("s_waitcnt lgkmcnt(0)\n\ts_barrier" ::: "memory");
        doIssue(2 * kt2 + 3, A1, B1);
        waitv();                                                        // batch 2*kt2+2 landed
    }
    doComp(A0, B0);                                                     // batch NS-2
    asm volatile("s_waitcnt lgkmcnt(0)\n\ts_barrier" ::: "memory");
    asm volatile("s_waitcnt vmcnt(0)\n\ts_barrier" ::: "memory");       // drain batch NS-1
    doComp(A1, B1);                                                     // batch NS-1

    // epilogue: out = (tanh(in+ca_in) * sigmoid(g+ca_g) + r + br) * sqrt(0.5)
    #pragma unroll
    for (int ms = 0; ms < 4; ++ms) {
        #pragma unroll
        for (int reg = 0; reg < 4; ++reg) {
            int m = m0 + wm * 64 + ms * 16 + q * 4 + reg;
            if (m >= M) continue;
            int n = n_start + (m >> lg);
            #pragma unroll
            for (int cs = 0; cs < 2; ++cs) {
                int co = co0 + wc * 32 + cs * 16 + r16;
                float vin = acc[0][ms][cs][reg] + ca_in[n * 256 + co];
                float vg  = acc[1][ms][cs][reg] + ca_g [n * 256 + co];
                float vr  = acc[2][ms][cs][reg] + br[co];
                float o = (tanh_f(vin) * sigm(vg) + vr) * SQRT_HALF;
                Y[(size_t)m * 256 + co] = f2bf(o);
            }
        }
    }
}

// ---------- head (unchanged, R3-verified) ----------
__global__ __launch_bounds__(256) void head_kernel(
        const u16* __restrict__ Y9, const float* __restrict__ pre_w, const float* __restrict__ pre_b,
        const float* __restrict__ mean_w, const float* __restrict__ mean_b,
        const float* __restrict__ std_w,  const float* __restrict__ std_b,
        const float* __restrict__ logit_w, const float* __restrict__ logit_b,
        float* __restrict__ out, int n_start) {
    __shared__ float xin[256];
    __shared__ float pre[256];
    int n_local = blockIdx.x;
    int n = n_start + n_local;
    int t = threadIdx.x;
    xin[t] = bf2f(Y9[(size_t)n_local * 256 + t]);
    __syncthreads();
    float s = pre_b[t];
    const float* wrow = pre_w + (size_t)t * 256;
    for (int c = 0; c < 256; ++c) s += xin[c] * wrow[c];
    pre[t] = fmaxf(s, 0.f);
    __syncthreads();
    if (t < 30) {
        int head = t / 10, mix = t % 10;
        const float* w  = head == 0 ? mean_w : (head == 1 ? std_w : logit_w);
        const float* bb = head == 0 ? mean_b : (head == 1 ? std_b : logit_b);
        float s2 = bb[mix];
        const float* wr = w + mix * 256;
        for (int c = 0; c < 256; ++c) s2 += pre[c] * wr[c];
        out[head * 4000 + n * 10 + mix] = s2;
    }
}

extern "C" void kernel_launch(void* const* d_in, const int* in_sizes, int n_in,
                              void* d_out, int out_size, void* d_ws, size_t ws_size,
                              hipStream_t stream) {
    const float* signal  = (const float*)d_in[0];
    const float* mgc     = (const float*)d_in[1];
    const float* cond_w  = (const float*)d_in[2];
    const float* cond_b  = (const float*)d_in[3];
    const float* l0_win  = (const float*)d_in[4];
    const float* l0_bin  = (const float*)d_in[5];
    const float* l0_wg   = (const float*)d_in[6];
    const float* l0_bg   = (const float*)d_in[7];
    const float* l0_wr   = (const float*)d_in[8];
    const float* l0_br   = (const float*)d_in[9];
    const float* lw_in   = (const float*)d_in[10];
    const float* lb_in   = (const float*)d_in[11];
    const float* lw_g    = (const float*)d_in[12];
    const float* lb_g    = (const float*)d_in[13];
    const float* lw_r    = (const float*)d_in[14];
    const float* lb_r    = (const float*)d_in[15];
    const float* cw_in   = (const float*)d_in[16];
    const float* cb_in   = (const float*)d_in[17];
    const float* cw_g    = (const float*)d_in[18];
    const float* cb_g    = (const float*)d_in[19];
    const float* pre_w   = (const float*)d_in[20];
    const float* pre_b   = (const float*)d_in[21];
    const float* mean_w  = (const float*)d_in[22];
    const float* mean_b  = (const float*)d_in[23];
    const float* std_w   = (const float*)d_in[24];
    const float* std_b   = (const float*)d_in[25];
    const float* logit_w = (const float*)d_in[26];
    const float* logit_b = (const float*)d_in[27];
    float* out = (float*)d_out;

    char* p = (char*)d_ws;
    auto alloc = [&](size_t bytes) -> char* {
        char* r = p; p += (bytes + 255) & ~(size_t)255; return r;
    };
    u16*   Wg    = (u16*)alloc(7077888);        // 9*3*256*512 bf16
    float* ca_in = (float*)alloc(4096000);      // 10*400*256 f32
    float* ca_g  = (float*)alloc(4096000);
    size_t fixedBytes = (size_t)(p - (char*)d_ws);

    int c = 1;
    while (c < 16 && fixedBytes + (104857600ull + 52428800ull) / c + 4096 > ws_size) c <<= 1;
    u16* bufA = (u16*)alloc(104857600ull / c);
    u16* bufB = (u16*)alloc(52428800ull / c);
    int n_count = 400 / c;

    prep_kernel<<<5008, 256, 0, stream>>>(mgc, cond_w, cond_b,
                                          cw_in, cb_in, cw_g, cb_g,
                                          l0_bin, lb_in, l0_bg, lb_g,
                                          lw_in, lw_g, lw_r, ca_in, ca_g, Wg);

    for (int ch = 0; ch < c; ++ch) {
        int n_start = ch * n_count;
        l0_kernel<<<n_count * 128, 256, 0, stream>>>(signal, l0_win, l0_wg, l0_wr, l0_br,
                                                     ca_in, ca_g, bufA, n_start);
        u16* src = bufA;
        u16* dst = bufB;
        for (int layer = 1; layer <= 9; ++layer) {
            int lg = 9 - layer;          // L_out = 1 << lg
            int M = n_count << lg;
            int mtiles = (M + 127) / 128;
            bool bk64 = (layer == 2) || (layer >= 5);
            if (bk64)
                gemm_layer_kernel<64><<<mtiles * 4, 256, 0, stream>>>(
                    src, Wg + (size_t)(layer - 1) * 3 * 131072,
                    ca_in + (size_t)layer * 102400, ca_g + (size_t)layer * 102400,
                    lb_r + (layer - 1) * 256, dst, M, lg, n_start);
            else
                gemm_layer_kernel<32><<<mtiles * 4, 256, 0, stream>>>(
                    src, Wg + (size_t)(layer - 1) * 3 * 131072,
                    ca_in + (size_t)layer * 102400, ca_g + (size_t)layer * 102400,
                    lb_r + (layer - 1) * 256, dst, M, lg, n_start);
            u16* tswap = src; src = dst; dst = tswap;
        }
        head_kernel<<<n_count, 256, 0, stream>>>(src, pre_w, pre_b, mean_w, mean_b,
                                                 std_w, std_b, logit_w, logit_b, out, n_start);
    }
}

// Round 6
// 545.920 us; speedup vs baseline: 2.9677x; 1.0393x over previous
//
#include <hip/hip_runtime.h>

typedef unsigned short u16;
using bf16x8 = __attribute__((ext_vector_type(8))) short;
using f32x4  = __attribute__((ext_vector_type(4))) float;

#define SQRT_HALF 0.70710678118f

__device__ __forceinline__ u16 f2bf(float f) {
    union { float f; unsigned int i; } x; x.f = f;
    unsigned int i = x.i;
    unsigned int r = (i + 0x7FFFu + ((i >> 16) & 1u)) >> 16;
    return (u16)r;
}
__device__ __forceinline__ float bf2f(u16 u) {
    union { unsigned int i; float f; } x; x.i = ((unsigned int)u) << 16; return x.f;
}
__device__ __forceinline__ float fastrcp(float x) {
    float r; asm("v_rcp_f32 %0, %1" : "=v"(r) : "v"(x)); return r;
}
__device__ __forceinline__ float sigm(float x) {
    return fastrcp(1.0f + __expf(-x));
}
__device__ __forceinline__ float tanh_f(float x) {
    float cx = fminf(fmaxf(x, -12.f), 12.f);
    float e = __expf(2.f * cx);
    return 1.0f - 2.0f * fastrcp(e + 1.0f);   // (e-1)/(e+1)
}

// async global->LDS, 16B per lane; LDS dest is wave-uniform base + lane*16.
__device__ __forceinline__ void gld16(const u16* g, u16* l) {
    __builtin_amdgcn_global_load_lds(
        (const __attribute__((address_space(1))) void*)g,
        (__attribute__((address_space(3))) void*)l,
        16, 0, 0);
}

// ---------- fused prep, full parallelism ----------
// blocks [0,4000): one block per (l,n) — cond row recomputed in LDS (cheap),
// then 256 threads each compute one (co) condadd pair. Same parallelism as
// the R3 split condadd (4000 blocks), no cond2 HBM round-trip.
// blocks [4000,8608): wreorder, one element per thread.
__global__ __launch_bounds__(256) void prep_kernel(
        const float* __restrict__ mgc, const float* __restrict__ cond_w,
        const float* __restrict__ cond_b,
        const float* __restrict__ cw_in, const float* __restrict__ cb_in,
        const float* __restrict__ cw_g,  const float* __restrict__ cb_g,
        const float* __restrict__ l0_bin, const float* __restrict__ lb_in,
        const float* __restrict__ l0_bg,  const float* __restrict__ lb_g,
        const float* __restrict__ lw_in, const float* __restrict__ lw_g,
        const float* __restrict__ lw_r,
        float* __restrict__ ca_in, float* __restrict__ ca_g, u16* __restrict__ Wg) {
    int b = blockIdx.x, t = threadIdx.x;
    if (b < 4000) {
        __shared__ float c2[60];
        int l = b / 400, n = b % 400;
        if (t < 60) {
            int f = n / 200;
            int jj = (n % 200) * 60 + t;
            float s = cond_b[jj];
            const float* wrow = cond_w + (size_t)jj * 60;
            const float* mrow = mgc + f * 60;
            for (int cc = 0; cc < 60; ++cc) s += mrow[cc] * wrow[cc];
            c2[t] = tanh_f(s);
        }
        __syncthreads();
        int co = t;
        float si = cb_in[l * 256 + co] + (l == 0 ? l0_bin[co] : lb_in[(l - 1) * 256 + co]);
        float sg = cb_g [l * 256 + co] + (l == 0 ? l0_bg [co] : lb_g [(l - 1) * 256 + co]);
        const float* wi = cw_in + (size_t)(l * 256 + co) * 60;
        const float* wg = cw_g  + (size_t)(l * 256 + co) * 60;
        for (int cc = 0; cc < 60; ++cc) {
            float cv = c2[cc];
            si += cv * wi[cc];
            sg += cv * wg[cc];
        }
        ca_in[l * 102400 + n * 256 + co] = si;
        ca_g [l * 102400 + n * 256 + co] = sg;
    } else {
        int idx = (b - 4000) * 256 + t;
        if (idx < 9 * 256 * 512) {
            int kk = idx & 511;
            int co = (idx >> 9) & 255;
            int l  = idx >> 17;
            int k = kk >> 8, ci = kk & 255;
            size_t src = ((size_t)(l * 256 + co) * 256 + ci) * 2 + k;
            size_t dst = (size_t)l * 3 * 131072 + (size_t)co * 512 + kk;
            Wg[dst]              = f2bf(lw_in[src]);
            Wg[dst + 131072]     = f2bf(lw_g[src]);
            Wg[dst + 2 * 131072] = f2bf(lw_r[src]);
        }
    }
}

// ---------- layer 0 (unchanged, R3-verified) ----------
__global__ void l0_kernel(const float* __restrict__ signal,
                          const float* __restrict__ l0_win, const float* __restrict__ l0_wg,
                          const float* __restrict__ l0_wr,  const float* __restrict__ l0_br,
                          const float* __restrict__ ca_in0, const float* __restrict__ ca_g0,
                          u16* __restrict__ Y0, int n_start) {
    int b = blockIdx.x;
    int tg = b & 127, n_local = b >> 7;
    int n = n_start + n_local;
    int ci = threadIdx.x;
    float wi0 = l0_win[ci * 2], wi1 = l0_win[ci * 2 + 1];
    float wg0 = l0_wg [ci * 2], wg1 = l0_wg [ci * 2 + 1];
    float wr0 = l0_wr [ci * 2], wr1 = l0_wr [ci * 2 + 1];
    float cain = ca_in0[n * 256 + ci], cag = ca_g0[n * 256 + ci], br = l0_br[ci];
    for (int i = 0; i < 4; ++i) {
        int t = tg * 4 + i;
        float s0 = signal[n + 2 * t];
        float s1 = signal[n + 2 * t + 1];
        float vin = wi0 * s0 + wi1 * s1 + cain;
        float vg  = wg0 * s0 + wg1 * s1 + cag;
        float vr  = wr0 * s0 + wr1 * s1 + br;
        float o = (tanh_f(vin) * sigm(vg) + vr) * SQRT_HALF;
        Y0[((size_t)n_local * 512 + t) * 256 + ci] = f2bf(o);
    }
}

// ---------- templated fused 3-conv GEMM + gating (layers 1..9) ----------
// BK=32: R3-verified geometry (LDS 40KB, 3 blk/CU, 16 K-steps, vmcnt(5)).
// BK=64: R0-verified swizzle geometry + gld16 pipeline (LDS 80KB, 2 blk/CU,
//        8 K-steps, vmcnt(10)) — halves barrier pairs for latency-floor layers.
template<int BK>
__global__ __launch_bounds__(256, BK == 32 ? 3 : 2) void gemm_layer_kernel(
        const u16* __restrict__ A, const u16* __restrict__ Wg,
        const float* __restrict__ ca_in, const float* __restrict__ ca_g,
        const float* __restrict__ br, u16* __restrict__ Y,
        int M, int lg, int n_start) {
    constexpr int AC  = BK / 16;        // A chunks per thread per batch
    constexpr int BC  = (3 * BK) / 32;  // B chunks per thread per batch
    constexpr int SL  = BK / 8;         // 16B slots per row
    constexpr int RSH = (BK == 32) ? 2 : 3;  // log2(slots per row)
    constexpr int NS  = 512 / BK;       // K-steps

    __shared__ __attribute__((aligned(16))) u16 A0[128 * BK];
    __shared__ __attribute__((aligned(16))) u16 A1[128 * BK];
    __shared__ __attribute__((aligned(16))) u16 B0[192 * BK];
    __shared__ __attribute__((aligned(16))) u16 B1[192 * BK];

    int mtiles = (M + 127) >> 7;
    int b = blockIdx.x;
    int mtile, cotile;
    if ((mtiles & 7) == 0) {
        int g = b >> 5, r = b & 31;         // 32-block group = 8 mtiles x 4 cotiles
        mtile  = g * 8 + (r & 7);           // r&7 == b%8 == XCD id
        cotile = r >> 3;
    } else {
        mtile = b >> 2; cotile = b & 3;
    }
    int m0  = mtile * 128;
    int co0 = cotile * 64;
    int tid = threadIdx.x;
    int lane = tid & 63, wave = tid >> 6;
    int wm = wave & 1, wc = wave >> 1;
    int q = lane >> 4, r16 = lane & 15;

    auto swz = [](int row) { return (BK == 32) ? ((row >> 1) & 3) : (row & 7); };

    const u16* agp[AC]; unsigned aoff[AC];
    #pragma unroll
    for (int i = 0; i < AC; ++i) {
        int c = i * 256 + tid;
        int row = c >> RSH, s = c & (SL - 1);
        int m = m0 + row;
        int msafe = m < M ? m : (M - 1);
        agp[i] = A + (size_t)msafe * 512 + (s ^ swz(row)) * 8;
        aoff[i] = (unsigned)c * 8;
    }
    const u16* bgp[BC]; unsigned boff[BC];
    #pragma unroll
    for (int i = 0; i < BC; ++i) {
        int c = i * 256 + tid;
        int row = c >> RSH, s = c & (SL - 1);
        int conv = row >> 6, col = row & 63;
        bgp[i] = Wg + ((size_t)conv * 256 + co0 + col) * 512 + (s ^ swz(row)) * 8;
        boff[i] = (unsigned)c * 8;
    }

    f32x4 acc[3][4][2] = {};

    auto doIssue = [&](int ktn, u16* Al, u16* Bl) {
        #pragma unroll
        for (int i = 0; i < AC; ++i) gld16(agp[i] + ktn * BK, &Al[aoff[i]]);
        #pragma unroll
        for (int i = 0; i < BC; ++i) gld16(bgp[i] + ktn * BK, &Bl[boff[i]]);
    };
    auto doComp = [&](const u16* Al, const u16* Bl) {
        #pragma unroll
        for (int ks = 0; ks < BK / 32; ++ks) {
            bf16x8 af[4], bfr[3][2];
            #pragma unroll
            for (int ms = 0; ms < 4; ++ms) {
                int row = wm * 64 + ms * 16 + r16;
                af[ms] = *(const bf16x8*)(&Al[row * BK + (((ks * 4 + q) ^ swz(row)) * 8)]);
            }
            #pragma unroll
            for (int cv = 0; cv < 3; ++cv)
                #pragma unroll
                for (int cs = 0; cs < 2; ++cs) {
                    int row = cv * 64 + wc * 32 + cs * 16 + r16;
                    bfr[cv][cs] = *(const bf16x8*)(&Bl[row * BK + (((ks * 4 + q) ^ swz(row)) * 8)]);
                }
            __builtin_amdgcn_s_setprio(1);
            #pragma unroll
            for (int cv = 0; cv < 3; ++cv)
                #pragma unroll
                for (int ms = 0; ms < 4; ++ms)
                    #pragma unroll
                    for (int cs = 0; cs < 2; ++cs)
                        acc[cv][ms][cs] = __builtin_amdgcn_mfma_f32_16x16x32_bf16(
                            af[ms], bfr[cv][cs], acc[cv][ms][cs], 0, 0, 0);
            __builtin_amdgcn_s_setprio(0);
        }
    };
    auto waitv = []() {
        if constexpr (BK == 32)
            asm volatile("s_waitcnt vmcnt(5)\n\ts_barrier" ::: "memory");
        else
            asm volatile("s_waitcnt vmcnt(10)\n\ts_barrier" ::: "memory");
    };

    // prologue: batches 0 and 1 in flight; wait only batch 0.
    doIssue(0, A0, B0);
    doIssue(1, A1, B1);
    waitv();

    #pragma unroll
    for (int kt2 = 0; kt2 < NS / 2 - 1; ++kt2) {
        doComp(A0, B0);                                                 // batch 2*kt2
        asm volatile("s_waitcnt lgkmcnt(0)\n\ts_barrier" ::: "memory"); // waves done reading A0/B0
        doIssue(2 * kt2 + 2, A0, B0);
        waitv();                                                        // batch 2*kt2+1 landed
        doComp(A1, B1);                                                 // batch 2*kt2+1
        asm volatile("s_waitcnt lgkmcnt(0)\n\ts_barrier" ::: "memory");
        doIssue(2 * kt2 + 3, A1, B1);
        waitv();                                                        // batch 2*kt2+2 landed
    }
    doComp(A0, B0);                                                     // batch NS-2
    asm volatile("s_waitcnt lgkmcnt(0)\n\ts_barrier" ::: "memory");
    asm volatile("s_waitcnt vmcnt(0)\n\ts_barrier" ::: "memory");       // drain batch NS-1
    doComp(A1, B1);                                                     // batch NS-1

    // epilogue: out = (tanh(in+ca_in) * sigmoid(g+ca_g) + r + br) * sqrt(0.5)
    #pragma unroll
    for (int ms = 0; ms < 4; ++ms) {
        #pragma unroll
        for (int reg = 0; reg < 4; ++reg) {
            int m = m0 + wm * 64 + ms * 16 + q * 4 + reg;
            if (m >= M) continue;
            int n = n_start + (m >> lg);
            #pragma unroll
            for (int cs = 0; cs < 2; ++cs) {
                int co = co0 + wc * 32 + cs * 16 + r16;
                float vin = acc[0][ms][cs][reg] + ca_in[n * 256 + co];
                float vg  = acc[1][ms][cs][reg] + ca_g [n * 256 + co];
                float vr  = acc[2][ms][cs][reg] + br[co];
                float o = (tanh_f(vin) * sigm(vg) + vr) * SQRT_HALF;
                Y[(size_t)m * 256 + co] = f2bf(o);
            }
        }
    }
}

// ---------- head (unchanged, R3-verified) ----------
__global__ __launch_bounds__(256) void head_kernel(
        const u16* __restrict__ Y9, const float* __restrict__ pre_w, const float* __restrict__ pre_b,
        const float* __restrict__ mean_w, const float* __restrict__ mean_b,
        const float* __restrict__ std_w,  const float* __restrict__ std_b,
        const float* __restrict__ logit_w, const float* __restrict__ logit_b,
        float* __restrict__ out, int n_start) {
    __shared__ float xin[256];
    __shared__ float pre[256];
    int n_local = blockIdx.x;
    int n = n_start + n_local;
    int t = threadIdx.x;
    xin[t] = bf2f(Y9[(size_t)n_local * 256 + t]);
    __syncthreads();
    float s = pre_b[t];
    const float* wrow = pre_w + (size_t)t * 256;
    for (int c = 0; c < 256; ++c) s += xin[c] * wrow[c];
    pre[t] = fmaxf(s, 0.f);
    __syncthreads();
    if (t < 30) {
        int head = t / 10, mix = t % 10;
        const float* w  = head == 0 ? mean_w : (head == 1 ? std_w : logit_w);
        const float* bb = head == 0 ? mean_b : (head == 1 ? std_b : logit_b);
        float s2 = bb[mix];
        const float* wr = w + mix * 256;
        for (int c = 0; c < 256; ++c) s2 += pre[c] * wr[c];
        out[head * 4000 + n * 10 + mix] = s2;
    }
}

extern "C" void kernel_launch(void* const* d_in, const int* in_sizes, int n_in,
                              void* d_out, int out_size, void* d_ws, size_t ws_size,
                              hipStream_t stream) {
    const float* signal  = (const float*)d_in[0];
    const float* mgc     = (const float*)d_in[1];
    const float* cond_w  = (const float*)d_in[2];
    const float* cond_b  = (const float*)d_in[3];
    const float* l0_win  = (const float*)d_in[4];
    const float* l0_bin  = (const float*)d_in[5];
    const float* l0_wg   = (const float*)d_in[6];
    const float* l0_bg   = (const float*)d_in[7];
    const float* l0_wr   = (const float*)d_in[8];
    const float* l0_br   = (const float*)d_in[9];
    const float* lw_in   = (const float*)d_in[10];
    const float* lb_in   = (const float*)d_in[11];
    const float* lw_g    = (const float*)d_in[12];
    const float* lb_g    = (const float*)d_in[13];
    const float* lw_r    = (const float*)d_in[14];
    const float* lb_r    = (const float*)d_in[15];
    const float* cw_in   = (const float*)d_in[16];
    const float* cb_in   = (const float*)d_in[17];
    const float* cw_g    = (const float*)d_in[18];
    const float* cb_g    = (const float*)d_in[19];
    const float* pre_w   = (const float*)d_in[20];
    const float* pre_b   = (const float*)d_in[21];
    const float* mean_w  = (const float*)d_in[22];
    const float* mean_b  = (const float*)d_in[23];
    const float* std_w   = (const float*)d_in[24];
    const float* std_b   = (const float*)d_in[25];
    const float* logit_w = (const float*)d_in[26];
    const float* logit_b = (const float*)d_in[27];
    float* out = (float*)d_out;

    char* p = (char*)d_ws;
    auto alloc = [&](size_t bytes) -> char* {
        char* r = p; p += (bytes + 255) & ~(size_t)255; return r;
    };
    u16*   Wg    = (u16*)alloc(7077888);        // 9*3*256*512 bf16
    float* ca_in = (float*)alloc(4096000);      // 10*400*256 f32
    float* ca_g  = (float*)alloc(4096000);
    size_t fixedBytes = (size_t)(p - (char*)d_ws);

    int c = 1;
    while (c < 16 && fixedBytes + (104857600ull + 52428800ull) / c + 4096 > ws_size) c <<= 1;
    u16* bufA = (u16*)alloc(104857600ull / c);
    u16* bufB = (u16*)alloc(52428800ull / c);
    int n_count = 400 / c;

    prep_kernel<<<8608, 256, 0, stream>>>(mgc, cond_w, cond_b,
                                          cw_in, cb_in, cw_g, cb_g,
                                          l0_bin, lb_in, l0_bg, lb_g,
                                          lw_in, lw_g, lw_r, ca_in, ca_g, Wg);

    for (int ch = 0; ch < c; ++ch) {
        int n_start = ch * n_count;
        l0_kernel<<<n_count * 128, 256, 0, stream>>>(signal, l0_win, l0_wg, l0_wr, l0_br,
                                                     ca_in, ca_g, bufA, n_start);
        u16* src = bufA;
        u16* dst = bufB;
        for (int layer = 1; layer <= 9; ++layer) {
            int lg = 9 - layer;          // L_out = 1 << lg
            int M = n_count << lg;
            int mtiles = (M + 127) / 128;
            bool bk64 = (layer == 2) || (layer >= 5);
            if (bk64)
                gemm_layer_kernel<64><<<mtiles * 4, 256, 0, stream>>>(
                    src, Wg + (size_t)(layer - 1) * 3 * 131072,
                    ca_in + (size_t)layer * 102400, ca_g + (size_t)layer * 102400,
                    lb_r + (layer - 1) * 256, dst, M, lg, n_start);
            else
                gemm_layer_kernel<32><<<mtiles * 4, 256, 0, stream>>>(
                    src, Wg + (size_t)(layer - 1) * 3 * 131072,
                    ca_in + (size_t)layer * 102400, ca_g + (size_t)layer * 102400,
                    lb_r + (layer - 1) * 256, dst, M, lg, n_start);
            u16* tswap = src; src = dst; dst = tswap;
        }
        head_kernel<<<n_count, 256, 0, stream>>>(src, pre_w, pre_b, mean_w, mean_b,
                                                 std_w, std_b, logit_w, logit_b, out, n_start);
    }
}

// Round 7
// 476.380 us; speedup vs baseline: 3.4009x; 1.1460x over previous
//
#include <hip/hip_runtime.h>

typedef unsigned short u16;
using bf16x8 = __attribute__((ext_vector_type(8))) short;
using f32x4  = __attribute__((ext_vector_type(4))) float;

#define SQRT_HALF 0.70710678118f

__device__ __forceinline__ u16 f2bf(float f) {
    union { float f; unsigned int i; } x; x.f = f;
    unsigned int i = x.i;
    unsigned int r = (i + 0x7FFFu + ((i >> 16) & 1u)) >> 16;
    return (u16)r;
}
__device__ __forceinline__ float bf2f(u16 u) {
    union { unsigned int i; float f; } x; x.i = ((unsigned int)u) << 16; return x.f;
}
__device__ __forceinline__ float fastrcp(float x) {
    float r; asm("v_rcp_f32 %0, %1" : "=v"(r) : "v"(x)); return r;
}
__device__ __forceinline__ float sigm(float x) {
    return fastrcp(1.0f + __expf(-x));
}
__device__ __forceinline__ float tanh_f(float x) {
    float cx = fminf(fmaxf(x, -12.f), 12.f);
    float e = __expf(2.f * cx);
    return 1.0f - 2.0f * fastrcp(e + 1.0f);   // (e-1)/(e+1)
}

// async global->LDS, 16B per lane; LDS dest is wave-uniform base + lane*16.
__device__ __forceinline__ void gld16(const u16* g, u16* l) {
    __builtin_amdgcn_global_load_lds(
        (const __attribute__((address_space(1))) void*)g,
        (__attribute__((address_space(3))) void*)l,
        16, 0, 0);
}

// ---------- one-time weight transposes (fix stride-240B gathers) ----------
// cond_wT[c][j]   = cond_w[j][c]        (60 x 12000)
// cwT_in[l][cc][co] = cw_in[l][co][cc]  (10 x 60 x 256), same for _g
__global__ __launch_bounds__(256) void xpose_kernel(
        const float* __restrict__ cond_w, const float* __restrict__ cw_in,
        const float* __restrict__ cw_g,
        float* __restrict__ cond_wT, float* __restrict__ cwT_in,
        float* __restrict__ cwT_g) {
    int idx = blockIdx.x * 256 + threadIdx.x;
    if (idx < 720000) {
        int c = idx / 12000, j = idx % 12000;
        cond_wT[idx] = cond_w[(size_t)j * 60 + c];
    } else if (idx < 720000 + 153600) {
        int i = idx - 720000;
        int l = i / 15360, r = i % 15360;       // 15360 = 60*256
        int cc = r / 256, co = r % 256;
        cwT_in[i] = cw_in[((size_t)(l * 256 + co)) * 60 + cc];
    } else if (idx < 720000 + 307200) {
        int i = idx - 720000 - 153600;
        int l = i / 15360, r = i % 15360;
        int cc = r / 256, co = r % 256;
        cwT_g[i] = cw_g[((size_t)(l * 256 + co)) * 60 + cc];
    }
}

// ---------- fused prep, coalesced ----------
// blocks [0,500): condadd for one (l, 8-n group). cond rows (8x60) computed
// in LDS from cond_wT (coalesced), then 256 threads (one co each) run the
// 60-MAC condadd with cwT reads coalesced across co and c2 broadcast reads.
// blocks [500,5108): wreorder, one element per thread.
__global__ __launch_bounds__(256) void prep_kernel(
        const float* __restrict__ mgc, const float* __restrict__ cond_wT,
        const float* __restrict__ cond_b,
        const float* __restrict__ cwT_in, const float* __restrict__ cb_in,
        const float* __restrict__ cwT_g,  const float* __restrict__ cb_g,
        const float* __restrict__ l0_bin, const float* __restrict__ lb_in,
        const float* __restrict__ l0_bg,  const float* __restrict__ lb_g,
        const float* __restrict__ lw_in, const float* __restrict__ lw_g,
        const float* __restrict__ lw_r,
        float* __restrict__ ca_in, float* __restrict__ ca_g, u16* __restrict__ Wg) {
    int b = blockIdx.x, t = threadIdx.x;
    if (b < 500) {
        __shared__ float c2[8][60];
        int l = b / 50, ng = b % 50;
        int n0 = ng * 8;                 // 8-group never straddles n=200
        int f = n0 / 200;
        for (int e = t; e < 480; e += 256) {
            int dn = e / 60, cc = e % 60;
            int jj = ((n0 + dn) % 200) * 60 + cc;
            float s = cond_b[jj];
            const float* mrow = mgc + f * 60;
            for (int c = 0; c < 60; ++c) s += mrow[c] * cond_wT[c * 12000 + jj];
            c2[dn][cc] = tanh_f(s);
        }
        __syncthreads();
        int co = t;
        float sib = cb_in[l * 256 + co] + (l == 0 ? l0_bin[co] : lb_in[(l - 1) * 256 + co]);
        float sgb = cb_g [l * 256 + co] + (l == 0 ? l0_bg [co] : lb_g [(l - 1) * 256 + co]);
        float si[8], sg[8];
        #pragma unroll
        for (int dn = 0; dn < 8; ++dn) { si[dn] = sib; sg[dn] = sgb; }
        const float* wiT = cwT_in + l * 15360 + co;
        const float* wgT = cwT_g  + l * 15360 + co;
        for (int cc = 0; cc < 60; ++cc) {
            float wiv = wiT[cc * 256];
            float wgv = wgT[cc * 256];
            #pragma unroll
            for (int dn = 0; dn < 8; ++dn) {
                float cv = c2[dn][cc];
                si[dn] += cv * wiv;
                sg[dn] += cv * wgv;
            }
        }
        #pragma unroll
        for (int dn = 0; dn < 8; ++dn) {
            ca_in[l * 102400 + (n0 + dn) * 256 + co] = si[dn];
            ca_g [l * 102400 + (n0 + dn) * 256 + co] = sg[dn];
        }
    } else {
        int idx = (b - 500) * 256 + t;
        if (idx < 9 * 256 * 512) {
            int kk = idx & 511;
            int co = (idx >> 9) & 255;
            int l  = idx >> 17;
            int k = kk >> 8, ci = kk & 255;
            size_t src = ((size_t)(l * 256 + co) * 256 + ci) * 2 + k;
            size_t dst = (size_t)l * 3 * 131072 + (size_t)co * 512 + kk;
            Wg[dst]              = f2bf(lw_in[src]);
            Wg[dst + 131072]     = f2bf(lw_g[src]);
            Wg[dst + 2 * 131072] = f2bf(lw_r[src]);
        }
    }
}

// ---------- layer 0 (unchanged, R3-verified) ----------
__global__ void l0_kernel(const float* __restrict__ signal,
                          const float* __restrict__ l0_win, const float* __restrict__ l0_wg,
                          const float* __restrict__ l0_wr,  const float* __restrict__ l0_br,
                          const float* __restrict__ ca_in0, const float* __restrict__ ca_g0,
                          u16* __restrict__ Y0, int n_start) {
    int b = blockIdx.x;
    int tg = b & 127, n_local = b >> 7;
    int n = n_start + n_local;
    int ci = threadIdx.x;
    float wi0 = l0_win[ci * 2], wi1 = l0_win[ci * 2 + 1];
    float wg0 = l0_wg [ci * 2], wg1 = l0_wg [ci * 2 + 1];
    float wr0 = l0_wr [ci * 2], wr1 = l0_wr [ci * 2 + 1];
    float cain = ca_in0[n * 256 + ci], cag = ca_g0[n * 256 + ci], br = l0_br[ci];
    for (int i = 0; i < 4; ++i) {
        int t = tg * 4 + i;
        float s0 = signal[n + 2 * t];
        float s1 = signal[n + 2 * t + 1];
        float vin = wi0 * s0 + wi1 * s1 + cain;
        float vg  = wg0 * s0 + wg1 * s1 + cag;
        float vr  = wr0 * s0 + wr1 * s1 + br;
        float o = (tanh_f(vin) * sigm(vg) + vr) * SQRT_HALF;
        Y0[((size_t)n_local * 512 + t) * 256 + ci] = f2bf(o);
    }
}

// ---------- templated fused 3-conv GEMM + gating (layers 1..9) ----------
// BK=32: R3-verified geometry (LDS 40KB, 3 blk/CU, 16 K-steps, vmcnt(5)).
// BK=64: R0-verified swizzle geometry + gld16 pipeline (LDS 80KB, 2 blk/CU,
//        8 K-steps, vmcnt(10)) — halves barrier pairs for latency-floor layers.
template<int BK>
__global__ __launch_bounds__(256, BK == 32 ? 3 : 2) void gemm_layer_kernel(
        const u16* __restrict__ A, const u16* __restrict__ Wg,
        const float* __restrict__ ca_in, const float* __restrict__ ca_g,
        const float* __restrict__ br, u16* __restrict__ Y,
        int M, int lg, int n_start) {
    constexpr int AC  = BK / 16;        // A chunks per thread per batch
    constexpr int BC  = (3 * BK) / 32;  // B chunks per thread per batch
    constexpr int SL  = BK / 8;         // 16B slots per row
    constexpr int RSH = (BK == 32) ? 2 : 3;  // log2(slots per row)
    constexpr int NS  = 512 / BK;       // K-steps

    __shared__ __attribute__((aligned(16))) u16 A0[128 * BK];
    __shared__ __attribute__((aligned(16))) u16 A1[128 * BK];
    __shared__ __attribute__((aligned(16))) u16 B0[192 * BK];
    __shared__ __attribute__((aligned(16))) u16 B1[192 * BK];

    int mtiles = (M + 127) >> 7;
    int b = blockIdx.x;
    int mtile, cotile;
    if ((mtiles & 7) == 0) {
        int g = b >> 5, r = b & 31;         // 32-block group = 8 mtiles x 4 cotiles
        mtile  = g * 8 + (r & 7);           // r&7 == b%8 == XCD id
        cotile = r >> 3;
    } else {
        mtile = b >> 2; cotile = b & 3;
    }
    int m0  = mtile * 128;
    int co0 = cotile * 64;
    int tid = threadIdx.x;
    int lane = tid & 63, wave = tid >> 6;
    int wm = wave & 1, wc = wave >> 1;
    int q = lane >> 4, r16 = lane & 15;

    auto swz = [](int row) { return (BK == 32) ? ((row >> 1) & 3) : (row & 7); };

    const u16* agp[AC]; unsigned aoff[AC];
    #pragma unroll
    for (int i = 0; i < AC; ++i) {
        int c = i * 256 + tid;
        int row = c >> RSH, s = c & (SL - 1);
        int m = m0 + row;
        int msafe = m < M ? m : (M - 1);
        agp[i] = A + (size_t)msafe * 512 + (s ^ swz(row)) * 8;
        aoff[i] = (unsigned)c * 8;
    }
    const u16* bgp[BC]; unsigned boff[BC];
    #pragma unroll
    for (int i = 0; i < BC; ++i) {
        int c = i * 256 + tid;
        int row = c >> RSH, s = c & (SL - 1);
        int conv = row >> 6, col = row & 63;
        bgp[i] = Wg + ((size_t)conv * 256 + co0 + col) * 512 + (s ^ swz(row)) * 8;
        boff[i] = (unsigned)c * 8;
    }

    f32x4 acc[3][4][2] = {};

    auto doIssue = [&](int ktn, u16* Al, u16* Bl) {
        #pragma unroll
        for (int i = 0; i < AC; ++i) gld16(agp[i] + ktn * BK, &Al[aoff[i]]);
        #pragma unroll
        for (int i = 0; i < BC; ++i) gld16(bgp[i] + ktn * BK, &Bl[boff[i]]);
    };
    auto doComp = [&](const u16* Al, const u16* Bl) {
        #pragma unroll
        for (int ks = 0; ks < BK / 32; ++ks) {
            bf16x8 af[4], bfr[3][2];
            #pragma unroll
            for (int ms = 0; ms < 4; ++ms) {
                int row = wm * 64 + ms * 16 + r16;
                af[ms] = *(const bf16x8*)(&Al[row * BK + (((ks * 4 + q) ^ swz(row)) * 8)]);
            }
            #pragma unroll
            for (int cv = 0; cv < 3; ++cv)
                #pragma unroll
                for (int cs = 0; cs < 2; ++cs) {
                    int row = cv * 64 + wc * 32 + cs * 16 + r16;
                    bfr[cv][cs] = *(const bf16x8*)(&Bl[row * BK + (((ks * 4 + q) ^ swz(row)) * 8)]);
                }
            __builtin_amdgcn_s_setprio(1);
            #pragma unroll
            for (int cv = 0; cv < 3; ++cv)
                #pragma unroll
                for (int ms = 0; ms < 4; ++ms)
                    #pragma unroll
                    for (int cs = 0; cs < 2; ++cs)
                        acc[cv][ms][cs] = __builtin_amdgcn_mfma_f32_16x16x32_bf16(
                            af[ms], bfr[cv][cs], acc[cv][ms][cs], 0, 0, 0);
            __builtin_amdgcn_s_setprio(0);
        }
    };
    auto waitv = []() {
        if constexpr (BK == 32)
            asm volatile("s_waitcnt vmcnt(5)\n\ts_barrier" ::: "memory");
        else
            asm volatile("s_waitcnt vmcnt(10)\n\ts_barrier" ::: "memory");
    };

    // prologue: batches 0 and 1 in flight; wait only batch 0.
    doIssue(0, A0, B0);
    doIssue(1, A1, B1);
    waitv();

    #pragma unroll
    for (int kt2 = 0; kt2 < NS / 2 - 1; ++kt2) {
        doComp(A0, B0);                                                 // batch 2*kt2
        asm volatile("s_waitcnt lgkmcnt(0)\n\ts_barrier" ::: "memory"); // waves done reading A0/B0
        doIssue(2 * kt2 + 2, A0, B0);
        waitv();                                                        // batch 2*kt2+1 landed
        doComp(A1, B1);                                                 // batch 2*kt2+1
        asm volatile("s_waitcnt lgkmcnt(0)\n\ts_barrier" ::: "memory");
        doIssue(2 * kt2 + 3, A1, B1);
        waitv();                                                        // batch 2*kt2+2 landed
    }
    doComp(A0, B0);                                                     // batch NS-2
    asm volatile("s_waitcnt lgkmcnt(0)\n\ts_barrier" ::: "memory");
    asm volatile("s_waitcnt vmcnt(0)\n\ts_barrier" ::: "memory");       // drain batch NS-1
    doComp(A1, B1);                                                     // batch NS-1

    // epilogue: out = (tanh(in+ca_in) * sigmoid(g+ca_g) + r + br) * sqrt(0.5)
    #pragma unroll
    for (int ms = 0; ms < 4; ++ms) {
        #pragma unroll
        for (int reg = 0; reg < 4; ++reg) {
            int m = m0 + wm * 64 + ms * 16 + q * 4 + reg;
            if (m >= M) continue;
            int n = n_start + (m >> lg);
            #pragma unroll
            for (int cs = 0; cs < 2; ++cs) {
                int co = co0 + wc * 32 + cs * 16 + r16;
                float vin = acc[0][ms][cs][reg] + ca_in[n * 256 + co];
                float vg  = acc[1][ms][cs][reg] + ca_g [n * 256 + co];
                float vr  = acc[2][ms][cs][reg] + br[co];
                float o = (tanh_f(vin) * sigm(vg) + vr) * SQRT_HALF;
                Y[(size_t)m * 256 + co] = f2bf(o);
            }
        }
    }
}

// ---------- head (unchanged, R3-verified) ----------
__global__ __launch_bounds__(256) void head_kernel(
        const u16* __restrict__ Y9, const float* __restrict__ pre_w, const float* __restrict__ pre_b,
        const float* __restrict__ mean_w, const float* __restrict__ mean_b,
        const float* __restrict__ std_w,  const float* __restrict__ std_b,
        const float* __restrict__ logit_w, const float* __restrict__ logit_b,
        float* __restrict__ out, int n_start) {
    __shared__ float xin[256];
    __shared__ float pre[256];
    int n_local = blockIdx.x;
    int n = n_start + n_local;
    int t = threadIdx.x;
    xin[t] = bf2f(Y9[(size_t)n_local * 256 + t]);
    __syncthreads();
    float s = pre_b[t];
    const float* wrow = pre_w + (size_t)t * 256;
    for (int c = 0; c < 256; ++c) s += xin[c] * wrow[c];
    pre[t] = fmaxf(s, 0.f);
    __syncthreads();
    if (t < 30) {
        int head = t / 10, mix = t % 10;
        const float* w  = head == 0 ? mean_w : (head == 1 ? std_w : logit_w);
        const float* bb = head == 0 ? mean_b : (head == 1 ? std_b : logit_b);
        float s2 = bb[mix];
        const float* wr = w + mix * 256;
        for (int c = 0; c < 256; ++c) s2 += pre[c] * wr[c];
        out[head * 4000 + n * 10 + mix] = s2;
    }
}

extern "C" void kernel_launch(void* const* d_in, const int* in_sizes, int n_in,
                              void* d_out, int out_size, void* d_ws, size_t ws_size,
                              hipStream_t stream) {
    const float* signal  = (const float*)d_in[0];
    const float* mgc     = (const float*)d_in[1];
    const float* cond_w  = (const float*)d_in[2];
    const float* cond_b  = (const float*)d_in[3];
    const float* l0_win  = (const float*)d_in[4];
    const float* l0_bin  = (const float*)d_in[5];
    const float* l0_wg   = (const float*)d_in[6];
    const float* l0_bg   = (const float*)d_in[7];
    const float* l0_wr   = (const float*)d_in[8];
    const float* l0_br   = (const float*)d_in[9];
    const float* lw_in   = (const float*)d_in[10];
    const float* lb_in   = (const float*)d_in[11];
    const float* lw_g    = (const float*)d_in[12];
    const float* lb_g    = (const float*)d_in[13];
    const float* lw_r    = (const float*)d_in[14];
    const float* lb_r    = (const float*)d_in[15];
    const float* cw_in   = (const float*)d_in[16];
    const float* cb_in   = (const float*)d_in[17];
    const float* cw_g    = (const float*)d_in[18];
    const float* cb_g    = (const float*)d_in[19];
    const float* pre_w   = (const float*)d_in[20];
    const float* pre_b   = (const float*)d_in[21];
    const float* mean_w  = (const float*)d_in[22];
    const float* mean_b  = (const float*)d_in[23];
    const float* std_w   = (const float*)d_in[24];
    const float* std_b   = (const float*)d_in[25];
    const float* logit_w = (const float*)d_in[26];
    const float* logit_b = (const float*)d_in[27];
    float* out = (float*)d_out;

    char* p = (char*)d_ws;
    auto alloc = [&](size_t bytes) -> char* {
        char* r = p; p += (bytes + 255) & ~(size_t)255; return r;
    };
    u16*   Wg      = (u16*)alloc(7077888);      // 9*3*256*512 bf16
    float* ca_in   = (float*)alloc(4096000);    // 10*400*256 f32
    float* ca_g    = (float*)alloc(4096000);
    float* cond_wT = (float*)alloc(2880000);    // 60*12000 f32
    float* cwT_in  = (float*)alloc(614400);     // 10*60*256 f32
    float* cwT_g   = (float*)alloc(614400);
    size_t fixedBytes = (size_t)(p - (char*)d_ws);

    int c = 1;
    while (c < 16 && fixedBytes + (104857600ull + 52428800ull) / c + 4096 > ws_size) c <<= 1;
    u16* bufA = (u16*)alloc(104857600ull / c);
    u16* bufB = (u16*)alloc(52428800ull / c);
    int n_count = 400 / c;

    xpose_kernel<<<4013, 256, 0, stream>>>(cond_w, cw_in, cw_g, cond_wT, cwT_in, cwT_g);
    prep_kernel<<<5108, 256, 0, stream>>>(mgc, cond_wT, cond_b,
                                          cwT_in, cb_in, cwT_g, cb_g,
                                          l0_bin, lb_in, l0_bg, lb_g,
                                          lw_in, lw_g, lw_r, ca_in, ca_g, Wg);

    for (int ch = 0; ch < c; ++ch) {
        int n_start = ch * n_count;
        l0_kernel<<<n_count * 128, 256, 0, stream>>>(signal, l0_win, l0_wg, l0_wr, l0_br,
                                                     ca_in, ca_g, bufA, n_start);
        u16* src = bufA;
        u16* dst = bufB;
        for (int layer = 1; layer <= 9; ++layer) {
            int lg = 9 - layer;          // L_out = 1 << lg
            int M = n_count << lg;
            int mtiles = (M + 127) / 128;
            bool bk64 = (layer == 2) || (layer >= 5);
            if (bk64)
                gemm_layer_kernel<64><<<mtiles * 4, 256, 0, stream>>>(
                    src, Wg + (size_t)(layer - 1) * 3 * 131072,
                    ca_in + (size_t)layer * 102400, ca_g + (size_t)layer * 102400,
                    lb_r + (layer - 1) * 256, dst, M, lg, n_start);
            else
                gemm_layer_kernel<32><<<mtiles * 4, 256, 0, stream>>>(
                    src, Wg + (size_t)(layer - 1) * 3 * 131072,
                    ca_in + (size_t)layer * 102400, ca_g + (size_t)layer * 102400,
                    lb_r + (layer - 1) * 256, dst, M, lg, n_start);
            u16* tswap = src; src = dst; dst = tswap;
        }
        head_kernel<<<n_count, 256, 0, stream>>>(src, pre_w, pre_b, mean_w, mean_b,
                                                 std_w, std_b, logit_w, logit_b, out, n_start);
    }
}